// Round 1
// baseline (113.371 us; speedup 1.0000x reference)
//
#include <hip/hip_runtime.h>

// HcSplitSinkhorn: B=32, S=16384, HC=4 -> nrows = 524288 rows of 24 fp32.
// out = [pre (nrows*4) | post (nrows*4) | comb (nrows*16)] fp32.

constexpr float EPSF  = 1e-6f;
constexpr float LOG2E = 1.4426950408889634f;

__device__ __forceinline__ float frcp(float x) { return __builtin_amdgcn_rcpf(x); }
__device__ __forceinline__ float fexp(float x) { return __builtin_amdgcn_exp2f(x * LOG2E); }

__global__ __launch_bounds__(256) void hc_sinkhorn_kernel(
    const float* __restrict__ mixes,
    const float* __restrict__ hc_scale,
    const float* __restrict__ hc_base,
    float* __restrict__ out_pre,
    float* __restrict__ out_post,
    float* __restrict__ out_comb,
    int nrows)
{
    const int r = blockIdx.x * blockDim.x + threadIdx.x;
    if (r >= nrows) return;

    // Wave-uniform params -> scalar loads (constant cache broadcast).
    const float s0 = hc_scale[0];
    const float s1 = hc_scale[1];
    const float s2 = hc_scale[2];

    const float4* src = reinterpret_cast<const float4*>(mixes) + (size_t)r * 6;
    const float4 vpre  = src[0];
    const float4 vpost = src[1];
    const float4 c0    = src[2];
    const float4 c1    = src[3];
    const float4 c2    = src[4];
    const float4 c3    = src[5];

    // ---- pre / post heads: sigmoid activations ----
    float pre[4]  = {vpre.x,  vpre.y,  vpre.z,  vpre.w};
    float post[4] = {vpost.x, vpost.y, vpost.z, vpost.w};
    #pragma unroll
    for (int i = 0; i < 4; ++i) {
        // sigmoid(x) = 1 / (1 + exp(-x))
        pre[i]  = frcp(1.0f + fexp(-(pre[i]  * s0 + hc_base[i]))) + EPSF;
        post[i] = 2.0f * frcp(1.0f + fexp(-(post[i] * s1 + hc_base[4 + i])));
    }

    // ---- comb: affine -> row softmax (+EPS) -> Sinkhorn ----
    float c[4][4];
    c[0][0] = c0.x * s2 + hc_base[ 8]; c[0][1] = c0.y * s2 + hc_base[ 9];
    c[0][2] = c0.z * s2 + hc_base[10]; c[0][3] = c0.w * s2 + hc_base[11];
    c[1][0] = c1.x * s2 + hc_base[12]; c[1][1] = c1.y * s2 + hc_base[13];
    c[1][2] = c1.z * s2 + hc_base[14]; c[1][3] = c1.w * s2 + hc_base[15];
    c[2][0] = c2.x * s2 + hc_base[16]; c[2][1] = c2.y * s2 + hc_base[17];
    c[2][2] = c2.z * s2 + hc_base[18]; c[2][3] = c2.w * s2 + hc_base[19];
    c[3][0] = c3.x * s2 + hc_base[20]; c[3][1] = c3.y * s2 + hc_base[21];
    c[3][2] = c3.z * s2 + hc_base[22]; c[3][3] = c3.w * s2 + hc_base[23];

    // Row softmax (axis=-1), then +EPS.
    #pragma unroll
    for (int i = 0; i < 4; ++i) {
        const float m  = fmaxf(fmaxf(c[i][0], c[i][1]), fmaxf(c[i][2], c[i][3]));
        const float e0 = fexp(c[i][0] - m);
        const float e1 = fexp(c[i][1] - m);
        const float e2 = fexp(c[i][2] - m);
        const float e3 = fexp(c[i][3] - m);
        const float rs = frcp(e0 + e1 + e2 + e3);   // jax softmax: no EPS in denom
        c[i][0] = e0 * rs + EPSF;
        c[i][1] = e1 * rs + EPSF;
        c[i][2] = e2 * rs + EPSF;
        c[i][3] = e3 * rs + EPSF;
    }

    // Sinkhorn: col-normalize, then 19 x (row-normalize, col-normalize).
    // All EPS-regularized: x / (sum + EPS).
    #pragma unroll
    for (int j = 0; j < 4; ++j) {
        const float s  = c[0][j] + c[1][j] + c[2][j] + c[3][j];
        const float rs = frcp(s + EPSF);
        c[0][j] *= rs; c[1][j] *= rs; c[2][j] *= rs; c[3][j] *= rs;
    }
    for (int it = 0; it < 19; ++it) {
        #pragma unroll
        for (int i = 0; i < 4; ++i) {
            const float s  = c[i][0] + c[i][1] + c[i][2] + c[i][3];
            const float rs = frcp(s + EPSF);
            c[i][0] *= rs; c[i][1] *= rs; c[i][2] *= rs; c[i][3] *= rs;
        }
        #pragma unroll
        for (int j = 0; j < 4; ++j) {
            const float s  = c[0][j] + c[1][j] + c[2][j] + c[3][j];
            const float rs = frcp(s + EPSF);
            c[0][j] *= rs; c[1][j] *= rs; c[2][j] *= rs; c[3][j] *= rs;
        }
    }

    // ---- stores (coalesced float4) ----
    reinterpret_cast<float4*>(out_pre)[r]  = make_float4(pre[0],  pre[1],  pre[2],  pre[3]);
    reinterpret_cast<float4*>(out_post)[r] = make_float4(post[0], post[1], post[2], post[3]);
    float4* oc = reinterpret_cast<float4*>(out_comb) + (size_t)r * 4;
    oc[0] = make_float4(c[0][0], c[0][1], c[0][2], c[0][3]);
    oc[1] = make_float4(c[1][0], c[1][1], c[1][2], c[1][3]);
    oc[2] = make_float4(c[2][0], c[2][1], c[2][2], c[2][3]);
    oc[3] = make_float4(c[3][0], c[3][1], c[3][2], c[3][3]);
}

extern "C" void kernel_launch(void* const* d_in, const int* in_sizes, int n_in,
                              void* d_out, int out_size, void* d_ws, size_t ws_size,
                              hipStream_t stream) {
    const float* mixes    = (const float*)d_in[0];
    const float* hc_scale = (const float*)d_in[1];
    const float* hc_base  = (const float*)d_in[2];
    // d_in[3] = hc_mult (4), d_in[4] = sinkhorn_iters (20) — fixed by problem shape.

    const int nrows = in_sizes[0] / 24;  // 524288
    float* out      = (float*)d_out;
    float* out_pre  = out;
    float* out_post = out + (size_t)nrows * 4;
    float* out_comb = out + (size_t)nrows * 8;

    const int block = 256;
    const int grid  = (nrows + block - 1) / block;
    hc_sinkhorn_kernel<<<grid, block, 0, stream>>>(
        mixes, hc_scale, hc_base, out_pre, out_post, out_comb, nrows);
}

// Round 7
// 112.853 us; speedup vs baseline: 1.0046x; 1.0046x over previous
//
#include <hip/hip_runtime.h>

// HcSplitSinkhorn: B=32, S=16384, HC=4 -> nrows = 524288 rows of 24 fp32.
// out = [pre (nrows*4) | post (nrows*4) | comb (nrows*16)] fp32.
//
// Round 2 design (resubmit x5; prior benches were acquisition timeouts):
// de-AoS the 96B-per-row layout through LDS so all global traffic is fully
// coalesced. Padded LDS strides 25/17 (coprime with 32 banks) make the
// per-row scalar accesses bank-conflict-free.

constexpr float EPSF  = 1e-6f;
constexpr float LOG2E = 1.4426950408889634f;

constexpr int RPB        = 256;  // rows per block == block size
constexpr int IN_STRIDE  = 25;   // floats; gcd(25,32)=1 -> conflict-free row reads
constexpr int OUT_STRIDE = 17;   // floats; gcd(17,32)=1 -> conflict-free row writes

__device__ __forceinline__ float frcp(float x) { return __builtin_amdgcn_rcpf(x); }
__device__ __forceinline__ float fexp(float x) { return __builtin_amdgcn_exp2f(x * LOG2E); }

__device__ __forceinline__ void compute_row(
    const float row[24], const float base[24],
    float s0, float s1, float s2,
    float pre[4], float post[4], float c[4][4])
{
    #pragma unroll
    for (int i = 0; i < 4; ++i) {
        pre[i]  = frcp(1.0f + fexp(-(row[i]     * s0 + base[i])))     + EPSF;
        post[i] = 2.0f * frcp(1.0f + fexp(-(row[4 + i] * s1 + base[4 + i])));
    }

    #pragma unroll
    for (int i = 0; i < 4; ++i)
        #pragma unroll
        for (int j = 0; j < 4; ++j)
            c[i][j] = row[8 + 4 * i + j] * s2 + base[8 + 4 * i + j];

    // Row softmax (axis=-1), then +EPS.
    #pragma unroll
    for (int i = 0; i < 4; ++i) {
        const float m  = fmaxf(fmaxf(c[i][0], c[i][1]), fmaxf(c[i][2], c[i][3]));
        const float e0 = fexp(c[i][0] - m);
        const float e1 = fexp(c[i][1] - m);
        const float e2 = fexp(c[i][2] - m);
        const float e3 = fexp(c[i][3] - m);
        const float rs = frcp(e0 + e1 + e2 + e3);   // jax softmax: no EPS in denom
        c[i][0] = e0 * rs + EPSF;
        c[i][1] = e1 * rs + EPSF;
        c[i][2] = e2 * rs + EPSF;
        c[i][3] = e3 * rs + EPSF;
    }

    // Sinkhorn: col-normalize, then 19 x (row-normalize, col-normalize).
    #pragma unroll
    for (int j = 0; j < 4; ++j) {
        const float rs = frcp(c[0][j] + c[1][j] + c[2][j] + c[3][j] + EPSF);
        c[0][j] *= rs; c[1][j] *= rs; c[2][j] *= rs; c[3][j] *= rs;
    }
    for (int it = 0; it < 19; ++it) {
        #pragma unroll
        for (int i = 0; i < 4; ++i) {
            const float rs = frcp(c[i][0] + c[i][1] + c[i][2] + c[i][3] + EPSF);
            c[i][0] *= rs; c[i][1] *= rs; c[i][2] *= rs; c[i][3] *= rs;
        }
        #pragma unroll
        for (int j = 0; j < 4; ++j) {
            const float rs = frcp(c[0][j] + c[1][j] + c[2][j] + c[3][j] + EPSF);
            c[0][j] *= rs; c[1][j] *= rs; c[2][j] *= rs; c[3][j] *= rs;
        }
    }
}

__global__ __launch_bounds__(256) void hc_sinkhorn_kernel(
    const float* __restrict__ mixes,
    const float* __restrict__ hc_scale,
    const float* __restrict__ hc_base,
    float* __restrict__ out_pre,
    float* __restrict__ out_post,
    float* __restrict__ out_comb,
    int nrows)
{
    __shared__ float lds[RPB * IN_STRIDE];   // 25600 B; comb staging reuses it (17408 B)

    const int t       = threadIdx.x;
    const int rowbase = blockIdx.x * RPB;

    // Wave-uniform params -> scalar loads.
    const float s0 = hc_scale[0];
    const float s1 = hc_scale[1];
    const float s2 = hc_scale[2];
    float base[24];
    #pragma unroll
    for (int k = 0; k < 24; ++k) base[k] = hc_base[k];

    if (rowbase + RPB <= nrows) {
        // ---------- fast path: full 256-row tile ----------
        // Phase A: coalesced global -> LDS (de-interleave, padded stride 25).
        const float4* src = reinterpret_cast<const float4*>(mixes) + (size_t)rowbase * 6;
        #pragma unroll
        for (int i = 0; i < 6; ++i) {
            const int    g = i * 256 + t;          // float4 index within tile
            const float4 v = src[g];
            const int    r = g / 6;
            const int    j = g % 6;
            float* dst = &lds[r * IN_STRIDE + j * 4];
            dst[0] = v.x; dst[1] = v.y; dst[2] = v.z; dst[3] = v.w;
        }
        __syncthreads();

        // Phase B: each thread reads its row (conflict-free).
        float row[24];
        #pragma unroll
        for (int k = 0; k < 24; ++k) row[k] = lds[t * IN_STRIDE + k];
        __syncthreads();   // all reads done before comb staging overwrites

        // Phase C: compute in registers.
        float pre[4], post[4], c[4][4];
        compute_row(row, base, s0, s1, s2, pre, post, c);

        // pre/post: already perfectly coalesced float4 stores.
        const int r = rowbase + t;
        reinterpret_cast<float4*>(out_pre)[r]  = make_float4(pre[0],  pre[1],  pre[2],  pre[3]);
        reinterpret_cast<float4*>(out_post)[r] = make_float4(post[0], post[1], post[2], post[3]);

        // Phase D: comb -> LDS (stride 17, conflict-free).
        #pragma unroll
        for (int i = 0; i < 4; ++i)
            #pragma unroll
            for (int j = 0; j < 4; ++j)
                lds[t * OUT_STRIDE + 4 * i + j] = c[i][j];
        __syncthreads();

        // Phase E: cooperative coalesced comb store.
        float4* dstc = reinterpret_cast<float4*>(out_comb) + (size_t)rowbase * 4;
        #pragma unroll
        for (int i = 0; i < 4; ++i) {
            const int g  = i * 256 + t;           // float4 index within 1024
            const int rr = g >> 2;
            const int jj = g & 3;
            const float* s = &lds[rr * OUT_STRIDE + 4 * jj];
            dstc[g] = make_float4(s[0], s[1], s[2], s[3]);
        }
    } else {
        // ---------- tail path: per-thread direct (absent at this shape) ----------
        const int r = rowbase + t;
        if (r < nrows) {
            const float4* src = reinterpret_cast<const float4*>(mixes) + (size_t)r * 6;
            float row[24];
            #pragma unroll
            for (int i = 0; i < 6; ++i) {
                const float4 v = src[i];
                row[4 * i]     = v.x; row[4 * i + 1] = v.y;
                row[4 * i + 2] = v.z; row[4 * i + 3] = v.w;
            }
            float pre[4], post[4], c[4][4];
            compute_row(row, base, s0, s1, s2, pre, post, c);
            reinterpret_cast<float4*>(out_pre)[r]  = make_float4(pre[0],  pre[1],  pre[2],  pre[3]);
            reinterpret_cast<float4*>(out_post)[r] = make_float4(post[0], post[1], post[2], post[3]);
            float4* oc = reinterpret_cast<float4*>(out_comb) + (size_t)r * 4;
            #pragma unroll
            for (int i = 0; i < 4; ++i)
                oc[i] = make_float4(c[i][0], c[i][1], c[i][2], c[i][3]);
        }
    }
}

extern "C" void kernel_launch(void* const* d_in, const int* in_sizes, int n_in,
                              void* d_out, int out_size, void* d_ws, size_t ws_size,
                              hipStream_t stream) {
    const float* mixes    = (const float*)d_in[0];
    const float* hc_scale = (const float*)d_in[1];
    const float* hc_base  = (const float*)d_in[2];

    const int nrows = in_sizes[0] / 24;  // 524288
    float* out      = (float*)d_out;
    float* out_pre  = out;
    float* out_post = out + (size_t)nrows * 4;
    float* out_comb = out + (size_t)nrows * 8;

    const int block = 256;
    const int grid  = (nrows + block - 1) / block;
    hc_sinkhorn_kernel<<<grid, block, 0, stream>>>(
        mixes, hc_scale, hc_base, out_pre, out_post, out_comb, nrows);
}